// Round 13
// baseline (150.922 us; speedup 1.0000x reference)
//
#include <hip/hip_runtime.h>
#include <hip/hip_bf16.h>

#define B_ 4
#define C_ 512
#define H_ 96
#define W_ 320
#define D_ 48
#define HW_ (H_*W_)

#define KC 32              // channels per chunk = MFMA K
#define NCHUNK (C_/KC)     // 16
#define WCOLS 112          // per-wave LDS cols: 32 L + 80 R (5 slots x 16)
#define CSTR 72            // bytes per LDS column (64B data + 8B pad; bank walk 18)
#define LDSB (WCOLS*CSTR)  // 8064 B per wave slice
#define NWV 5              // 5 independent waves per workgroup (occupancy packing)
#define NT (NWV*64)        // 320 threads
#define NUW 224            // staging units per wave: 28 col-quads x 8 ch-quads
#define SIT 4              // ceil(224/64)
#define EPS2 36            // epilogue row stride in floats (16B-aligned)
#define NBLK (B_*H_*2)     // 768 blocks = 8 XCDs x 96 exactly

typedef __attribute__((ext_vector_type(8))) short bf16x8;
typedef __attribute__((ext_vector_type(4))) float f32x4;

__device__ __forceinline__ unsigned cvt2(float lo, float hi) {
  union { __hip_bfloat162 h2; unsigned u; } u;
  u.h2 = __float22bfloat162_rn(make_float2(lo, hi));   // v_cvt_pk_bf16_f32 (RNE)
  return u.u;
}
// Column-major [col][k] bf16, stride 72 B, no swizzle (R7/R10/R12-verified):
// 18*lc mod 32 bijects lc=0..15 onto the 16 even banks -> fragment reads
// (b64 pairs at col*72 + 16*lg, +8) sit exactly at the 4-access/bank floor.
__device__ __forceinline__ int ldsoff(int col, int q) {   // q = 8B k-granule
  return col * CSTR + (q << 3);
}

__global__ __launch_bounds__(NT)
void cost_volume_mfma(const float* __restrict__ Lp,
                      const float* __restrict__ Rp,
                      float* __restrict__ out) {
  __shared__ __align__(16) char lds[NWV * LDSB];   // 40320 B -> 3 blocks/CU
  const int ln = threadIdx.x;
  const int wv = ln >> 6;              // wave 0..4 — fully independent
  const int lane = ln & 63;
  // T1: bijective XCD-chunked swizzle (768 % 8 == 0). Both half-row blocks of
  // a (b,h) row land on ONE XCD -> R-halo re-reads hit that XCD's 4MB L2.
  // (R11/R12-verified: FETCH 455 -> 250 MB.)
  const int bid = blockIdx.x;
  const int wk = (bid & 7) * (NBLK / 8) + (bid >> 3);
  const int half = wk & 1;
  const int bh = wk >> 1;
  const int b = bh / H_, h = bh % H_;
  const int lc = lane & 15;
  const int lg = (lane >> 4) & 3;
  const int t2 = NWV * half + wv;      // this wave's tile-pair within the row
  const int m0 = 2 * t2;               // owns m-tiles m0, m0+1
  char* slds = lds + wv * LDSB;        // private LDS slice — no cross-wave deps

  // ---- staging unit descriptors: u -> (c4 = u%28, chq = u/28) ----
  // local col = 4*c4: c4<8 -> L tiles (global x = 16*m0 + col);
  // c4>=8 -> R slot dnp=(c4-8)>>2 (tile jn = m0+1-dnp), col-in-slot 4*((c4-8)&3)
  const float* sp[SIT];
  int dstb[SIT];
  bool sact[SIT];
#pragma unroll
  for (int it = 0; it < SIT; ++it) {
    const int u = lane + 64 * it;
    bool a = (u < NUW);
    const int uc = a ? u : 0;
    const int c4 = uc % 28, chq = uc / 28;
    const int col = 4 * c4;
    int x;
    const float* bp;
    if (c4 < 8) { x = 16 * m0 + col; bp = Lp; }
    else {
      const int dnp = (c4 - 8) >> 2, jn = m0 + 1 - dnp;
      x = 16 * jn + 4 * ((c4 - 8) & 3);
      bp = Rp;
      a = a && (jn >= 0);
    }
    if (x < 0) x = 0;
    sp[it] = bp + ((size_t)(b * C_ + 4 * chq) * H_ + h) * W_ + x;
    dstb[it] = ldsoff(col, chq);
    sact[it] = a;
  }

  float4 sreg[SIT][4];   // one full chunk in flight (64 VGPR)

#define SLOAD() \
  _Pragma("unroll") for (int it = 0; it < SIT; ++it) { \
    if (sact[it]) { \
      _Pragma("unroll") for (int l = 0; l < 4; ++l) \
        sreg[it][l] = *(const float4*)(sp[it] + (size_t)l * HW_); \
    } \
    sp[it] += (size_t)KC * HW_; \
  }

#define SWRITE() \
  _Pragma("unroll") for (int it = 0; it < SIT; ++it) if (sact[it]) { \
    char* p = slds + dstb[it]; \
    uint2 v; \
    v.x = cvt2(sreg[it][0].x, sreg[it][1].x); v.y = cvt2(sreg[it][2].x, sreg[it][3].x); \
    *(uint2*)(p) = v; \
    v.x = cvt2(sreg[it][0].y, sreg[it][1].y); v.y = cvt2(sreg[it][2].y, sreg[it][3].y); \
    *(uint2*)(p + CSTR) = v; \
    v.x = cvt2(sreg[it][0].z, sreg[it][1].z); v.y = cvt2(sreg[it][2].z, sreg[it][3].z); \
    *(uint2*)(p + 2 * CSTR) = v; \
    v.x = cvt2(sreg[it][0].w, sreg[it][1].w); v.y = cvt2(sreg[it][2].w, sreg[it][3].w); \
    *(uint2*)(p + 3 * CSTR) = v; \
  }

  // ---- fragment byte offsets (slice-local cols; R7-verified mapping) ----
  const int aoff0 = ldsoff(lc, 2 * lg);          // L tile m0
  const int aoff1 = ldsoff(16 + lc, 2 * lg);     // L tile m0+1
  int boff[5];
  bool bval[5];
#pragma unroll
  for (int dnp = 0; dnp < 5; ++dnp) {
    boff[dnp] = ldsoff(32 + 16 * dnp + lc, 2 * lg);
    bval[dnp] = (m0 + 1 - dnp) >= 0;
  }

  union FragU { uint2 h[2]; bf16x8 v; };
#define FREAD(fr, off) do { FragU _f; \
  _f.h[0] = *(const uint2*)(slds + (off)); \
  _f.h[1] = *(const uint2*)(slds + (off) + 8); fr = _f.v; } while (0)

  f32x4 acc[2][4];
#pragma unroll
  for (int ml = 0; ml < 2; ++ml)
#pragma unroll
    for (int dn = 0; dn < 4; ++dn) acc[ml][dn] = (f32x4){0.f, 0.f, 0.f, 0.f};

  // ---- barrier-free K loop (per-wave): program order + in-order DS
  // gives write(k+1)-after-read(k); loads stay in flight across iterations ----
  SLOAD();     // chunk 0
  SWRITE();    // waits chunk-0 loads (once)
  SLOAD();     // chunk 1 in flight
  for (int k = 0; k < NCHUNK; ++k) {
    bf16x8 a0, a1;
    FREAD(a0, aoff0);
    FREAD(a1, aoff1);
    bf16x8 bf[5];
#pragma unroll
    for (int dnp = 0; dnp < 5; ++dnp)
      if (bval[dnp]) FREAD(bf[dnp], boff[dnp]);
#pragma unroll
    for (int dn = 0; dn < 4; ++dn) {
      if (bval[dn + 1])
        acc[0][dn] = __builtin_amdgcn_mfma_f32_16x16x32_bf16(a0, bf[dn + 1], acc[0][dn], 0, 0, 0);
      if (bval[dn])
        acc[1][dn] = __builtin_amdgcn_mfma_f32_16x16x32_bf16(a1, bf[dn], acc[1][dn], 0, 0, 0);
    }
    if (k < NCHUNK - 1) SWRITE();          // chunk k+1 (loads issued 1 iter ago)
    if (k < NCHUNK - 2) SLOAD();           // chunk k+2 into freed regs
  }

  // ---- epilogue: per-wave transpose in its own slice -> coalesced stores ----
  __syncthreads();
  float* ep = (float*)slds;                // [48][EPS2] = 6912 B (fits in 8064)
#pragma unroll
  for (int e = 0; e < (D_ * EPS2 + 63) / 64; ++e) {
    const int i = lane + 64 * e;
    if (i < D_ * EPS2) ep[i] = 0.f;
  }
  __syncthreads();
  const float scale = 1.f / 512.f;
#pragma unroll
  for (int ml = 0; ml < 2; ++ml) {
#pragma unroll
    for (int dn = 0; dn < 4; ++dn) {
      if ((m0 + ml - dn) >= 0) {
#pragma unroll
        for (int q = 0; q < 4; ++q) {
          const int i = 4 * lg + q;        // C/D row = 4*(lane>>4) + reg
          const int d = 16 * dn + i - lc;  // d = w - w'
          if (d >= 0 && d < D_)
            ep[d * EPS2 + 16 * ml + i] = acc[ml][dn][q] * scale;
        }
      }
    }
  }
  __syncthreads();
  // per wave: 48 d-rows x 8 float4 (32 w-cols) = 384 units = 6 per lane
#pragma unroll
  for (int e = 0; e < 6; ++e) {
    const int u = lane + 64 * e;
    const int d = u >> 3, c4 = u & 7;
    const float4 v = *(const float4*)(ep + d * EPS2 + 4 * c4);
    float* o = out + (((size_t)b * D_ + d) * H_ + h) * W_ + 16 * m0 + 4 * c4;
    *(float4*)o = v;
  }
}

extern "C" void kernel_launch(void* const* d_in, const int* in_sizes, int n_in,
                              void* d_out, int out_size, void* d_ws, size_t ws_size,
                              hipStream_t stream) {
  const float* left  = (const float*)d_in[0];
  const float* right = (const float*)d_in[1];
  float* outp = (float*)d_out;
  cost_volume_mfma<<<dim3(NBLK), dim3(NT), 0, stream>>>(left, right, outp);
}

// Round 14
// 125.893 us; speedup vs baseline: 1.1988x; 1.1988x over previous
//
#include <hip/hip_runtime.h>
#include <hip/hip_bf16.h>

#define B_ 4
#define C_ 512
#define H_ 96
#define W_ 320
#define D_ 48
#define HW_ (H_*W_)

#define KC 32              // channels per chunk = MFMA K
#define NCHUNK (C_/KC)     // 16
#define WCOLS 112          // per-wave LDS cols: 32 L + 80 R (5 slots x 16)
#define CSTR 72            // bytes per LDS column (64B data + 8B pad; bank walk 18)
#define LDSB (WCOLS*CSTR)  // 8064 B — single wave, single buffer
#define NT 64              // ONE wave per block: no barriers in K-loop
#define NUW 224            // staging units: 28 col-quads x 8 ch-quads
#define SIT 4              // ceil(224/64)
#define EPS2 36            // epilogue row stride in floats (16B-aligned)
#define NBLK (B_*H_*10)    // 3840 blocks = 8 XCDs x 480 exactly

typedef __attribute__((ext_vector_type(8))) short bf16x8;
typedef __attribute__((ext_vector_type(4))) float f32x4;

__device__ __forceinline__ unsigned cvt2(float lo, float hi) {
  union { __hip_bfloat162 h2; unsigned u; } u;
  u.h2 = __float22bfloat162_rn(make_float2(lo, hi));   // v_cvt_pk_bf16_f32 (RNE)
  return u.u;
}
// Column-major [col][k] bf16, stride 72 B, no swizzle (R7/R10/R12-verified):
// 18*lc mod 32 bijects lc=0..15 onto the 16 even banks -> fragment reads
// (b64 pairs at col*72 + 16*lg, +8) sit exactly at the 4-access/bank floor.
__device__ __forceinline__ int ldsoff(int col, int q) {   // q = 8B k-granule
  return col * CSTR + (q << 3);
}

// (NT, 1): min ONE wave per EU -> VGPR budget up to 256. R7/R12's implicit
// high-occupancy budget (64-92 VGPR) forced the scheduler to serialize the
// 16 staging loads into dependent micro-groups — the root cause of the
// ~11k-cycle chunk latency. We trade resident waves for per-wave MLP.
__global__ __launch_bounds__(NT, 1)
void cost_volume_mfma(const float* __restrict__ Lp,
                      const float* __restrict__ Rp,
                      float* __restrict__ out) {
  __shared__ __align__(16) char lds[LDSB];
  const int ln = threadIdx.x;
  // T1: bijective XCD-chunked swizzle (3840 % 8 == 0). All 10 tile-blocks of
  // a (b,h) row land on ONE XCD -> R-halo re-reads hit that XCD's 4MB L2.
  // (R11/R12-verified: FETCH 455 -> 250 MB.)
  const int bid = blockIdx.x;
  const int wk = (bid & 7) * (NBLK / 8) + (bid >> 3);
  const int t2 = wk % 10;
  const int bh = wk / 10;
  const int b = bh / H_, h = bh % H_;
  const int lc = ln & 15;
  const int lg = (ln >> 4) & 3;
  const int m0 = 2 * t2;               // this wave owns m-tiles m0, m0+1

  // ---- staging unit descriptors: u -> (c4 = u%28, chq = u/28) ----
  // local col = 4*c4: c4<8 -> L tiles (global x = 16*m0 + col);
  // c4>=8 -> R slot dnp=(c4-8)>>2 (tile jn = m0+1-dnp), col-in-slot 4*((c4-8)&3)
  const float* sp[SIT];
  int dstb[SIT];
  bool sact[SIT];
#pragma unroll
  for (int it = 0; it < SIT; ++it) {
    const int u = ln + 64 * it;
    bool a = (u < NUW);
    const int uc = a ? u : 0;
    const int c4 = uc % 28, chq = uc / 28;
    const int col = 4 * c4;
    int x;
    const float* bp;
    if (c4 < 8) { x = 16 * m0 + col; bp = Lp; }
    else {
      const int dnp = (c4 - 8) >> 2, jn = m0 + 1 - dnp;
      x = 16 * jn + 4 * ((c4 - 8) & 3);
      bp = Rp;
      a = a && (jn >= 0);
    }
    if (x < 0) x = 0;
    sp[it] = bp + ((size_t)(b * C_ + 4 * chq) * H_ + h) * W_ + x;
    dstb[it] = ldsoff(col, chq);
    sact[it] = a;
  }

  float4 sreg[SIT][4];   // one full chunk in flight (64 VGPR, now allowed to live)

#define SLOAD() \
  _Pragma("unroll") for (int it = 0; it < SIT; ++it) { \
    if (sact[it]) { \
      _Pragma("unroll") for (int l = 0; l < 4; ++l) \
        sreg[it][l] = *(const float4*)(sp[it] + (size_t)l * HW_); \
    } \
    sp[it] += (size_t)KC * HW_; \
  }

// Pin: no instruction may cross -> all 16 loads issue HERE, before compute,
// and stay in flight until next iteration's SWRITE wait.
#define PIN() __builtin_amdgcn_sched_barrier(0)

#define SWRITE() \
  _Pragma("unroll") for (int it = 0; it < SIT; ++it) if (sact[it]) { \
    char* p = lds + dstb[it]; \
    uint2 v; \
    v.x = cvt2(sreg[it][0].x, sreg[it][1].x); v.y = cvt2(sreg[it][2].x, sreg[it][3].x); \
    *(uint2*)(p) = v; \
    v.x = cvt2(sreg[it][0].y, sreg[it][1].y); v.y = cvt2(sreg[it][2].y, sreg[it][3].y); \
    *(uint2*)(p + CSTR) = v; \
    v.x = cvt2(sreg[it][0].z, sreg[it][1].z); v.y = cvt2(sreg[it][2].z, sreg[it][3].z); \
    *(uint2*)(p + 2 * CSTR) = v; \
    v.x = cvt2(sreg[it][0].w, sreg[it][1].w); v.y = cvt2(sreg[it][2].w, sreg[it][3].w); \
    *(uint2*)(p + 3 * CSTR) = v; \
  }

  // ---- fragment byte offsets (wave-local cols; R7-verified mapping) ----
  const int aoff0 = ldsoff(lc, 2 * lg);          // L tile m0
  const int aoff1 = ldsoff(16 + lc, 2 * lg);     // L tile m0+1
  int boff[5];
  bool bval[5];
#pragma unroll
  for (int dnp = 0; dnp < 5; ++dnp) {
    boff[dnp] = ldsoff(32 + 16 * dnp + lc, 2 * lg);
    bval[dnp] = (m0 + 1 - dnp) >= 0;
  }

  union FragU { uint2 h[2]; bf16x8 v; };
#define FREAD(fr, off) do { FragU _f; \
  _f.h[0] = *(const uint2*)(lds + (off)); \
  _f.h[1] = *(const uint2*)(lds + (off) + 8); fr = _f.v; } while (0)

  f32x4 acc[2][4];
#pragma unroll
  for (int ml = 0; ml < 2; ++ml)
#pragma unroll
    for (int dn = 0; dn < 4; ++dn) acc[ml][dn] = (f32x4){0.f, 0.f, 0.f, 0.f};

  // ---- barrier-free K loop (single wave): program order + in-order DS
  // gives write(k+1)-after-read(k); all 16 next-chunk loads pinned in flight
  // across each iteration's compute ----
  SLOAD();     // chunk 0
  SWRITE();    // waits chunk-0 loads (once)
  SLOAD();     // chunk 1 in flight
  PIN();
  for (int k = 0; k < NCHUNK; ++k) {
    bf16x8 a0, a1;
    FREAD(a0, aoff0);
    FREAD(a1, aoff1);
    bf16x8 bf[5];
#pragma unroll
    for (int dnp = 0; dnp < 5; ++dnp)
      if (bval[dnp]) FREAD(bf[dnp], boff[dnp]);
#pragma unroll
    for (int dn = 0; dn < 4; ++dn) {
      if (bval[dn + 1])
        acc[0][dn] = __builtin_amdgcn_mfma_f32_16x16x32_bf16(a0, bf[dn + 1], acc[0][dn], 0, 0, 0);
      if (bval[dn])
        acc[1][dn] = __builtin_amdgcn_mfma_f32_16x16x32_bf16(a1, bf[dn], acc[1][dn], 0, 0, 0);
    }
    if (k < NCHUNK - 1) SWRITE();          // chunk k+1 (loads issued 1 iter ago)
    if (k < NCHUNK - 2) { SLOAD(); PIN(); }  // chunk k+2: all 16 issue here
  }

  // ---- epilogue: per-wave transpose through LDS -> coalesced stores ----
  __syncthreads();
  float* ep = (float*)lds;                 // [48][EPS2] = 6912 B (fits in 8064)
#pragma unroll
  for (int e = 0; e < (D_ * EPS2 + NT - 1) / NT; ++e) {
    const int i = ln + NT * e;
    if (i < D_ * EPS2) ep[i] = 0.f;
  }
  __syncthreads();
  const float scale = 1.f / 512.f;
#pragma unroll
  for (int ml = 0; ml < 2; ++ml) {
#pragma unroll
    for (int dn = 0; dn < 4; ++dn) {
      if ((m0 + ml - dn) >= 0) {
#pragma unroll
        for (int q = 0; q < 4; ++q) {
          const int i = 4 * lg + q;        // C/D row = 4*(lane>>4) + reg
          const int d = 16 * dn + i - lc;  // d = w - w'
          if (d >= 0 && d < D_)
            ep[d * EPS2 + 16 * ml + i] = acc[ml][dn][q] * scale;
        }
      }
    }
  }
  __syncthreads();
  // 48 d-rows x 8 float4 (32 w-cols) = 384 units = 6 per lane
#pragma unroll
  for (int e = 0; e < 6; ++e) {
    const int u = ln + NT * e;
    const int d = u >> 3, c4 = u & 7;
    const float4 v = *(const float4*)(ep + d * EPS2 + 4 * c4);
    float* o = out + (((size_t)b * D_ + d) * H_ + h) * W_ + 16 * m0 + 4 * c4;
    *(float4*)o = v;
  }
}

extern "C" void kernel_launch(void* const* d_in, const int* in_sizes, int n_in,
                              void* d_out, int out_size, void* d_ws, size_t ws_size,
                              hipStream_t stream) {
  const float* left  = (const float*)d_in[0];
  const float* right = (const float*)d_in[1];
  float* outp = (float*)d_out;
  cost_volume_mfma<<<dim3(NBLK), dim3(NT), 0, stream>>>(left, right, outp);
}